// Round 13
// baseline (624.237 us; speedup 1.0000x reference)
//
#include <hip/hip_runtime.h>

#define FD   128        // feature dim (floats)
#define FDH  64         // uints per bf16 row / u16s per fp8 row
#define EPSN 1e-8f
#define RCC  0.5f
#define SCAN_TPB 256
#define SCAN_ELEMS 1024

typedef unsigned int uint;
typedef unsigned short u16;
typedef unsigned char u8;
typedef float fx2 __attribute__((ext_vector_type(2)));
typedef int iv4 __attribute__((ext_vector_type(4)));
typedef int iv2 __attribute__((ext_vector_type(2)));

#if __has_builtin(__builtin_amdgcn_cvt_scalef32_pk_f32_fp4) && __has_builtin(__builtin_amdgcn_cvt_scalef32_pk_fp4_f32)
#define USE_FP4 1
#define COLSHIFT 6      // fX rows are 64 B (fp4)
#define L1SHIFT 1       // g8 rows are 128 B -> extra <<1
#else
#define USE_FP4 0
#define COLSHIFT 7      // fX rows are 128 B (fp8)
#define L1SHIFT 0
#endif

__device__ __forceinline__ float wave_sum(float x) {
#pragma unroll
    for (int off = 32; off > 0; off >>= 1) x += __shfl_xor(x, off);
    return x;
}

__device__ __forceinline__ uint packbf2(float a, float b) {
    uint ua = __float_as_uint(a); ua += 0x7fffu + ((ua >> 16) & 1u);
    uint ub = __float_as_uint(b); ub += 0x7fffu + ((ub >> 16) & 1u);
    return (ua >> 16) | (ub & 0xffff0000u);
}
__device__ __forceinline__ float2 unpackbf2(uint v) {
    return make_float2(__uint_as_float(v << 16), __uint_as_float(v & 0xffff0000u));
}
__device__ __forceinline__ u16 packfp8(float a, float b) { // 2x f32 -> 2x OCP e4m3
    return (u16)__builtin_amdgcn_cvt_pk_fp8_f32(a, b, 0, false);
}

// ---------------- Pass A: linked-list insert (1 atomicExch per insertion) + fused prep ----
__global__ void passA(const int* __restrict__ ub_u, const int* __restrict__ ub_b,
                      const int* __restrict__ ui_u, const int* __restrict__ ui_i,
                      const int* __restrict__ bi_b, const int* __restrict__ bi_i,
                      const float* __restrict__ uf, const float* __restrict__ bf,
                      const float* __restrict__ itf,
                      int E_UB, int E_UI, int E_BI, int NU, int NB, int n1, int n2, int NT,
                      int nblk_edges,
                      int* __restrict__ head, int2* __restrict__ pairLL,
                      uint* __restrict__ fini16, float* __restrict__ normf) {
    if ((int)blockIdx.x < nblk_edges) {
        int e = blockIdx.x * blockDim.x + threadIdx.x;
        if (e < E_UB) {
            int a = ub_u[e], b = ub_b[e] + NU;
            int s0 = 2 * e;
            int p0 = atomicExch(&head[a], s0);
            int p1 = atomicExch(&head[b], s0 + 1);
            iv4 rec = {p0, b, p1, a};
            __builtin_nontemporal_store(rec, (iv4*)pairLL + e);
        } else if (e < E_UB + E_UI) {
            int f = e - E_UB;
            int a = ui_u[f], bl = ui_i[f] + NU;     // graph-local col ids
            int s0 = 2 * E_UB + 2 * f;
            int p0 = atomicExch(&head[n1 + a], s0);
            int p1 = atomicExch(&head[n1 + bl], s0 + 1);
            iv4 rec = {p0, bl, p1, a};
            __builtin_nontemporal_store(rec, (iv4*)pairLL + (E_UB + f));
        } else if (e < E_UB + E_UI + E_BI) {
            int g = e - E_UB - E_UI;
            int s = 2 * E_UB + 2 * E_UI + g;
            int p = atomicExch(&head[n1 + n2 + bi_b[g]], s);
            iv2 rec = {p, bi_i[g]};
            __builtin_nontemporal_store(rec, (iv2*)pairLL + s);
        }
    } else {
        int w = (((int)blockIdx.x - nblk_edges) * blockDim.x + threadIdx.x) >> 6;
        int lane = threadIdx.x & 63;
        if (w >= NT) return;
        const float* src = (w < NU) ? uf + (size_t)w * FD
                         : (w < NU + NB) ? bf + (size_t)(w - NU) * FD
                         : itf + (size_t)(w - NU - NB) * FD;
        float2 x = ((const float2*)src)[lane];
        float ss = wave_sum(x.x * x.x + x.y * x.y);
        float nrm = sqrtf(ss);
        float inv = 1.0f / fmaxf(nrm, 1e-12f);
        __builtin_nontemporal_store(packbf2(x.x * inv, x.y * inv),
                                    &fini16[(size_t)w * FDH + lane]);
        if (lane == 0) normf[w] = nrm;
    }
}

// ---------------- Pass B: chain length -> deg, dinv ----------------
__global__ void passB(const int* __restrict__ head, const int2* __restrict__ pairLL,
                      int NN, int n12, int* __restrict__ deg, float* __restrict__ dinv) {
    int r = blockIdx.x * blockDim.x + threadIdx.x;
    if (r > NN) return;
    if (r == NN) { deg[NN] = 0; return; }
    int c = 0;
    int s = head[r];
    while (s >= 0) { c++; s = pairLL[s].x; }
    deg[r] = c;
    if (r < n12) dinv[r] = 1.0f / (sqrtf((float)c) + EPSN);
}

// ---------------- exclusive scan ----------------
__global__ void scan_a(const int* __restrict__ in, int* __restrict__ out,
                       int* __restrict__ bsum, int nelem) {
    __shared__ int tsum[SCAN_TPB];
    int tid = threadIdx.x;
    int base = blockIdx.x * SCAN_ELEMS + tid * 4;
    int v0 = (base + 0 < nelem) ? in[base + 0] : 0;
    int v1 = (base + 1 < nelem) ? in[base + 1] : 0;
    int v2 = (base + 2 < nelem) ? in[base + 2] : 0;
    int v3 = (base + 3 < nelem) ? in[base + 3] : 0;
    int s = v0 + v1 + v2 + v3;
    tsum[tid] = s;
    __syncthreads();
    for (int off = 1; off < SCAN_TPB; off <<= 1) {
        int y = (tid >= off) ? tsum[tid - off] : 0;
        __syncthreads();
        tsum[tid] += y;
        __syncthreads();
    }
    int excl = tsum[tid] - s;
    if (tid == SCAN_TPB - 1) bsum[blockIdx.x] = tsum[SCAN_TPB - 1];
    if (base + 0 < nelem) out[base + 0] = excl;
    excl += v0;
    if (base + 1 < nelem) out[base + 1] = excl;
    excl += v1;
    if (base + 2 < nelem) out[base + 2] = excl;
    excl += v2;
    if (base + 3 < nelem) out[base + 3] = excl;
}

__global__ void scan_b(int* __restrict__ bsum, int nb) {   // nb <= 512
    __shared__ int sm[512];
    int tid = threadIdx.x;
    int v = (tid < nb) ? bsum[tid] : 0;
    sm[tid] = v;
    __syncthreads();
    for (int off = 1; off < 512; off <<= 1) {
        int y = (tid >= off) ? sm[tid - off] : 0;
        __syncthreads();
        sm[tid] += y;
        __syncthreads();
    }
    if (tid < nb) bsum[tid] = sm[tid] - v;
}

__global__ void scan_c(int* __restrict__ out, const int* __restrict__ bsum, int nelem) {
    int base = blockIdx.x * SCAN_ELEMS + threadIdx.x * 4;
    int add = bsum[blockIdx.x];
#pragma unroll
    for (int k = 0; k < 4; ++k)
        if (base + k < nelem) out[base + k] += add;
}

// ---------------- Pass C (+ fused conv_g8): flatten chains to CSR ----------------
// UB/UI rows: cols[pos] = col<<COLSHIFT. BI rows: bi2[pos-S1] = {col<<8, wt}.
// conv part: g8[r] = fp8(fini[node(r)] * dinv[r] * norm[node(r)])
__global__ void passC_conv(const int* __restrict__ head, const int2* __restrict__ pairLL,
                           const int* __restrict__ rowptr, const float* __restrict__ bi_vals,
                           int NN, int n12, int S1,
                           int* __restrict__ cols, int2* __restrict__ bi2,
                           const uint* __restrict__ fini16, const float* __restrict__ normf,
                           const float* __restrict__ dinv,
                           int n1, int NU, int NB, u16* __restrict__ g8, int nblkC) {
    if ((int)blockIdx.x < nblkC) {
        int r = blockIdx.x * blockDim.x + threadIdx.x;
        if (r >= NN) return;
        int pos = rowptr[r];
        int s = head[r];
        if (r < n12) {
            while (s >= 0) { int2 p = pairLL[s]; cols[pos++] = p.y << COLSHIFT; s = p.x; }
        } else {
            while (s >= 0) {
                int2 p = pairLL[s];
                bi2[pos - S1] = make_int2(p.y << 8, __float_as_int(bi_vals[s - S1]));
                pos++; s = p.x;
            }
        }
    } else {
        int w = (((int)blockIdx.x - nblkC) * blockDim.x + threadIdx.x) >> 6;
        int lane = threadIdx.x & 63;
        if (w >= n12) return;
        int node = (w < n1) ? w : ((w - n1 < NU) ? (w - n1) : (w - n1 + NB));
        float sc = dinv[w] * normf[node];
        float2 f = unpackbf2(fini16[(size_t)node * FDH + lane]);
        g8[(size_t)w * FDH + lane] = packfp8(f.x * sc, f.y * sc);
    }
}

// ======== 2-rows-per-wave fp8 gather core (L1; also L2 fallback) ========
#define ACC8(XU)  {                                                              \
    fx2 _pa = __builtin_amdgcn_cvt_pk_f32_fp8((int)(XU).x, false);               \
    fx2 _pb = __builtin_amdgcn_cvt_pk_f32_fp8((int)(XU).x, true);                \
    fx2 _pc = __builtin_amdgcn_cvt_pk_f32_fp8((int)(XU).y, false);               \
    fx2 _pd = __builtin_amdgcn_cvt_pk_f32_fp8((int)(XU).y, true);                \
    a0 += _pa.x; a1 += _pa.y; a2 += _pb.x; a3 += _pb.y;                          \
    a4 += _pc.x; a5 += _pc.y; a6 += _pd.x; a7 += _pd.y; }

#define GATHER8(TAB, SH)                                                         \
    float a0=0.f,a1=0.f,a2=0.f,a3=0.f,a4=0.f,a5=0.f,a6=0.f,a7=0.f;               \
    {                                                                            \
      int base = lane & 32;                                                      \
      for (int cs = s; cs < e; cs += 32) {                                       \
        int cnt = e - cs; if (cnt > 32) cnt = 32;                                \
        int colv = (l31 < cnt) ? cols[cs + l31] : 0;                             \
        int p = 0;                                                               \
        for (; 2 * p + 8 <= cnt; p += 4) {                                       \
            int o0 = __shfl(colv, base + 2 * p + sub) << (SH);                   \
            int o1 = __shfl(colv, base + 2 * p + 2 + sub) << (SH);               \
            int o2 = __shfl(colv, base + 2 * p + 4 + sub) << (SH);               \
            int o3 = __shfl(colv, base + 2 * p + 6 + sub) << (SH);               \
            uint2 x0 = *(const uint2*)(TAB + o0);                                \
            uint2 x1 = *(const uint2*)(TAB + o1);                                \
            uint2 x2 = *(const uint2*)(TAB + o2);                                \
            uint2 x3 = *(const uint2*)(TAB + o3);                                \
            ACC8(x0) ACC8(x1) ACC8(x2) ACC8(x3)                                  \
        }                                                                        \
        for (; 2 * p + 2 <= cnt; ++p) {                                          \
            int o = __shfl(colv, base + 2 * p + sub) << (SH);                    \
            uint2 x = *(const uint2*)(TAB + o);                                  \
            ACC8(x)                                                              \
        }                                                                        \
        if (2 * p < cnt) {                                                       \
            int o = __shfl(colv, base + 2 * p) << (SH);                          \
            if (sub == 0) { uint2 x = *(const uint2*)(TAB + o); ACC8(x) }        \
        }                                                                        \
      }                                                                          \
    }                                                                            \
    a0 += __shfl_xor(a0, 16); a1 += __shfl_xor(a1, 16);                          \
    a2 += __shfl_xor(a2, 16); a3 += __shfl_xor(a3, 16);                          \
    a4 += __shfl_xor(a4, 16); a5 += __shfl_xor(a5, 16);                          \
    a6 += __shfl_xor(a6, 16); a7 += __shfl_xor(a7, 16);

#if USE_FP4
// ======== fp4 gather core (L2): 64-B rows, per-edge scale via fma ========
#define ACC4(XU, SV)  {                                                          \
    fx2 _f;                                                                      \
    _f = __builtin_amdgcn_cvt_scalef32_pk_f32_fp4((XU), 1.0f, 0);                \
    a0 = fmaf(SV, _f.x, a0); a1 = fmaf(SV, _f.y, a1);                            \
    _f = __builtin_amdgcn_cvt_scalef32_pk_f32_fp4((XU), 1.0f, 1);                \
    a2 = fmaf(SV, _f.x, a2); a3 = fmaf(SV, _f.y, a3);                            \
    _f = __builtin_amdgcn_cvt_scalef32_pk_f32_fp4((XU), 1.0f, 2);                \
    a4 = fmaf(SV, _f.x, a4); a5 = fmaf(SV, _f.y, a5);                            \
    _f = __builtin_amdgcn_cvt_scalef32_pk_f32_fp4((XU), 1.0f, 3);                \
    a6 = fmaf(SV, _f.x, a6); a7 = fmaf(SV, _f.y, a7); }

#define GATHER4(TAB, FSC)                                                        \
    float a0=0.f,a1=0.f,a2=0.f,a3=0.f,a4=0.f,a5=0.f,a6=0.f,a7=0.f;               \
    {                                                                            \
      int base = lane & 32;                                                      \
      for (int cs = s; cs < e; cs += 32) {                                       \
        int cnt = e - cs; if (cnt > 32) cnt = 32;                                \
        int colv = (l31 < cnt) ? cols[cs + l31] : 0;                             \
        float sclv = (FSC)[colv >> 6];                                           \
        int p = 0;                                                               \
        for (; 2 * p + 8 <= cnt; p += 4) {                                       \
            int o0 = __shfl(colv, base + 2 * p + sub);                           \
            int o1 = __shfl(colv, base + 2 * p + 2 + sub);                       \
            int o2 = __shfl(colv, base + 2 * p + 4 + sub);                       \
            int o3 = __shfl(colv, base + 2 * p + 6 + sub);                       \
            float s0v = __shfl(sclv, base + 2 * p + sub);                        \
            float s1v = __shfl(sclv, base + 2 * p + 2 + sub);                    \
            float s2v = __shfl(sclv, base + 2 * p + 4 + sub);                    \
            float s3v = __shfl(sclv, base + 2 * p + 6 + sub);                    \
            uint x0 = *(const uint*)(TAB + o0);                                  \
            uint x1 = *(const uint*)(TAB + o1);                                  \
            uint x2 = *(const uint*)(TAB + o2);                                  \
            uint x3 = *(const uint*)(TAB + o3);                                  \
            ACC4(x0, s0v) ACC4(x1, s1v) ACC4(x2, s2v) ACC4(x3, s3v)              \
        }                                                                        \
        for (; 2 * p + 2 <= cnt; ++p) {                                          \
            int o = __shfl(colv, base + 2 * p + sub);                            \
            float sv = __shfl(sclv, base + 2 * p + sub);                         \
            uint x = *(const uint*)(TAB + o);                                    \
            ACC4(x, sv)                                                          \
        }                                                                        \
        if (2 * p < cnt) {                                                       \
            int o = __shfl(colv, base + 2 * p);                                  \
            float sv = __shfl(sclv, base + 2 * p);                               \
            if (sub == 0) { uint x = *(const uint*)(TAB + o); ACC4(x, sv) }      \
        }                                                                        \
      }                                                                          \
    }                                                                            \
    a0 += __shfl_xor(a0, 16); a1 += __shfl_xor(a1, 16);                          \
    a2 += __shfl_xor(a2, 16); a3 += __shfl_xor(a3, 16);                          \
    a4 += __shfl_xor(a4, 16); a5 += __shfl_xor(a5, 16);                          \
    a6 += __shfl_xor(a6, 16); a7 += __shfl_xor(a7, 16);
#endif

// ---------------- Layer 1: gather pre-scaled fp8 g8; emit facc16 + fX(+fscale) --------
__global__ void spmm_L1(const int* __restrict__ rowptr, const int* __restrict__ cols,
                        const float* __restrict__ dinv, const float* __restrict__ normf,
                        const uint* __restrict__ fini16, const u16* __restrict__ g8,
                        uint* __restrict__ facc16, uint* __restrict__ fX,
                        float* __restrict__ fscale,
                        int n1, int NU, int NB, int n12) {
    int wv = (blockIdx.x * blockDim.x + threadIdx.x) >> 6;
    int lane = threadIdx.x & 63;
    int hw = lane >> 5, l31 = lane & 31, sub = (lane >> 4) & 1, t = lane & 15;
    int r = 2 * wv + hw;
    if (r >= n12) return;
    int s = rowptr[r], e = rowptr[r + 1];
    bool ui = (r >= n1);
    int node = ui ? ((r - n1 < NU) ? (r - n1) : (r - n1 + NB)) : r;
    float dr = dinv[r];
    uint4 iu = ((const uint4*)(fini16 + (size_t)node * FDH))[t];
    float nr = normf[node];
    const u8* tab = (const u8*)g8 + ((size_t)(ui ? n1 : 0) << 7) + (t << 3);
    GATHER8(tab, L1SHIFT)
    float2 i01 = unpackbf2(iu.x), i23 = unpackbf2(iu.y);
    float2 i45 = unpackbf2(iu.z), i67 = unpackbf2(iu.w);
    float v0 = (dr * a0 + RCC * i01.x) * 0.5f;
    float v1 = (dr * a1 + RCC * i01.y) * 0.5f;
    float v2 = (dr * a2 + RCC * i23.x) * 0.5f;
    float v3 = (dr * a3 + RCC * i23.y) * 0.5f;
    float v4 = (dr * a4 + RCC * i45.x) * 0.5f;
    float v5 = (dr * a5 + RCC * i45.y) * 0.5f;
    float v6 = (dr * a6 + RCC * i67.x) * 0.5f;
    float v7 = (dr * a7 + RCC * i67.y) * 0.5f;
    float sq = v0*v0 + v1*v1 + v2*v2 + v3*v3 + v4*v4 + v5*v5 + v6*v6 + v7*v7;
#pragma unroll
    for (int off = 8; off > 0; off >>= 1) sq += __shfl_xor(sq, off);
    float inv = 1.0f / fmaxf(sqrtf(sq), 1e-12f);
    v0 *= inv; v1 *= inv; v2 *= inv; v3 *= inv;
    v4 *= inv; v5 *= inv; v6 *= inv; v7 *= inv;
    if (sub == 0) {
        uint4 fa;
        fa.x = packbf2(fmaf(i01.x, nr, v0), fmaf(i01.y, nr, v1));
        fa.y = packbf2(fmaf(i23.x, nr, v2), fmaf(i23.y, nr, v3));
        fa.z = packbf2(fmaf(i45.x, nr, v4), fmaf(i45.y, nr, v5));
        fa.w = packbf2(fmaf(i67.x, nr, v6), fmaf(i67.y, nr, v7));
        ((uint4*)(facc16 + (size_t)r * FDH))[t] = fa;
#if USE_FP4
        float q0 = v0 * dr, q1 = v1 * dr, q2 = v2 * dr, q3 = v3 * dr;
        float q4 = v4 * dr, q5 = v5 * dr, q6 = v6 * dr, q7 = v7 * dr;
        float m = fmaxf(fmaxf(fmaxf(fabsf(q0), fabsf(q1)), fmaxf(fabsf(q2), fabsf(q3))),
                        fmaxf(fmaxf(fabsf(q4), fabsf(q5)), fmaxf(fabsf(q6), fabsf(q7))));
        m = fmaxf(m, __shfl_xor(m, 1));
        m = fmaxf(m, __shfl_xor(m, 2));
        m = fmaxf(m, __shfl_xor(m, 4));
        m = fmaxf(m, __shfl_xor(m, 8));
        float sc = fmaxf(m, 1e-30f) * (1.0f / 6.0f);
        float isc = 1.0f / sc;
        if (t == 0) fscale[r] = sc;
        int xa = __builtin_amdgcn_cvt_scalef32_pk_fp4_f32(0,  q0 * isc, q1 * isc, 1.0f, 0);
        xa = __builtin_amdgcn_cvt_scalef32_pk_fp4_f32(xa, q2 * isc, q3 * isc, 1.0f, 1);
        xa = __builtin_amdgcn_cvt_scalef32_pk_fp4_f32(xa, q4 * isc, q5 * isc, 1.0f, 2);
        xa = __builtin_amdgcn_cvt_scalef32_pk_fp4_f32(xa, q6 * isc, q7 * isc, 1.0f, 3);
        fX[(size_t)r * 16 + t] = (uint)xa;
#else
        int xa = __builtin_amdgcn_cvt_pk_fp8_f32(v0 * dr, v1 * dr, 0, false);
        xa = __builtin_amdgcn_cvt_pk_fp8_f32(v2 * dr, v3 * dr, xa, true);
        int xb = __builtin_amdgcn_cvt_pk_fp8_f32(v4 * dr, v5 * dr, 0, false);
        xb = __builtin_amdgcn_cvt_pk_fp8_f32(v6 * dr, v7 * dr, xb, true);
        ((uint2*)(fX + (size_t)r * 32))[t] = make_uint2((uint)xa, (uint)xb);
#endif
    }
}

// ---------------- Layer 2: gather from fX (fp4 w/ per-row scale, or fp8 fallback) -----
__global__ void spmm_L2(const int* __restrict__ rowptr, const int* __restrict__ cols,
                        const float* __restrict__ dinv, const uint* __restrict__ fini16,
                        const uint* __restrict__ facc16, const uint* __restrict__ fX,
                        const float* __restrict__ fscale,
                        uint* __restrict__ items16, float* __restrict__ outp,
                        int n1, int NU, int NB, int n12) {
    int wv = (blockIdx.x * blockDim.x + threadIdx.x) >> 6;
    int lane = threadIdx.x & 63;
    int hw = lane >> 5, l31 = lane & 31, sub = (lane >> 4) & 1, t = lane & 15;
    int r = 2 * wv + hw;
    if (r >= n12) return;
    int s = rowptr[r], e = rowptr[r + 1];
    bool ui = (r >= n1);
    int node = ui ? ((r - n1 < NU) ? (r - n1) : (r - n1 + NB)) : r;
    float dr = dinv[r];
    uint4 iu = ((const uint4*)(fini16 + (size_t)node * FDH))[t];
    uint4 au = ((const uint4*)(facc16 + (size_t)r * FDH))[t];
#if USE_FP4
    const u8* tab = (const u8*)fX + ((size_t)(ui ? n1 : 0) << 6) + (t << 2);
    const float* fsc = fscale + (ui ? n1 : 0);
    GATHER4(tab, fsc)
#else
    const u8* tab = (const u8*)fX + ((size_t)(ui ? n1 : 0) << 7) + (t << 3);
    GATHER8(tab, 0)
#endif
    float2 i01 = unpackbf2(iu.x), i23 = unpackbf2(iu.y);
    float2 i45 = unpackbf2(iu.z), i67 = unpackbf2(iu.w);
    float v0 = (dr * a0 + RCC * i01.x) * (1.0f / 3.0f);
    float v1 = (dr * a1 + RCC * i01.y) * (1.0f / 3.0f);
    float v2 = (dr * a2 + RCC * i23.x) * (1.0f / 3.0f);
    float v3 = (dr * a3 + RCC * i23.y) * (1.0f / 3.0f);
    float v4 = (dr * a4 + RCC * i45.x) * (1.0f / 3.0f);
    float v5 = (dr * a5 + RCC * i45.y) * (1.0f / 3.0f);
    float v6 = (dr * a6 + RCC * i67.x) * (1.0f / 3.0f);
    float v7 = (dr * a7 + RCC * i67.y) * (1.0f / 3.0f);
    float sq = v0*v0 + v1*v1 + v2*v2 + v3*v3 + v4*v4 + v5*v5 + v6*v6 + v7*v7;
#pragma unroll
    for (int off = 8; off > 0; off >>= 1) sq += __shfl_xor(sq, off);
    float inv = 1.0f / fmaxf(sqrtf(sq), 1e-12f);
    v0 *= inv; v1 *= inv; v2 *= inv; v3 *= inv;
    v4 *= inv; v5 *= inv; v6 *= inv; v7 *= inv;
    float2 a01 = unpackbf2(au.x), a23 = unpackbf2(au.y);
    float2 a45 = unpackbf2(au.z), a67 = unpackbf2(au.w);
    float n0 = a01.x + v0, n1v = a01.y + v1, n2v = a23.x + v2, n3 = a23.y + v3;
    float n4 = a45.x + v4, n5 = a45.y + v5, n6 = a67.x + v6, n7 = a67.y + v7;
    if (sub == 0) {
        if (!ui) {
            size_t dst = (r < NU) ? (size_t)(NU + r) : (size_t)(2 * NU + NB + (r - NU));
            float* orow = outp + dst * FD;
            ((float4*)orow)[2 * t]     = make_float4(n0, n1v, n2v, n3);
            ((float4*)orow)[2 * t + 1] = make_float4(n4, n5, n6, n7);
        } else {
            int l = r - n1;
            if (l < NU) {
                float* orow = outp + (size_t)l * FD;
                ((float4*)orow)[2 * t]     = make_float4(n0, n1v, n2v, n3);
                ((float4*)orow)[2 * t + 1] = make_float4(n4, n5, n6, n7);
            } else {
                uint4 it;
                it.x = packbf2(n0, n1v);
                it.y = packbf2(n2v, n3);
                it.z = packbf2(n4, n5);
                it.w = packbf2(n6, n7);
                ((uint4*)(items16 + (size_t)(l - NU) * FDH))[t] = it;
            }
        }
    }
}

// ---------------- BI gather from bf16 items (2 rows/wave, packed col+wt) --------------
#define FMA8(XU, W) { float2 _f;                                                 \
    _f = unpackbf2((XU).x); a0 = fmaf(W, _f.x, a0); a1 = fmaf(W, _f.y, a1);      \
    _f = unpackbf2((XU).y); a2 = fmaf(W, _f.x, a2); a3 = fmaf(W, _f.y, a3);      \
    _f = unpackbf2((XU).z); a4 = fmaf(W, _f.x, a4); a5 = fmaf(W, _f.y, a5);      \
    _f = unpackbf2((XU).w); a6 = fmaf(W, _f.x, a6); a7 = fmaf(W, _f.y, a7); }

__global__ void bi_gather(const int* __restrict__ rowptr, const int2* __restrict__ bi2,
                          int S1, const uint* __restrict__ items16,
                          float* __restrict__ outb, int nb) {
    int wv = (blockIdx.x * blockDim.x + threadIdx.x) >> 6;
    int lane = threadIdx.x & 63;
    int hw = lane >> 5, l31 = lane & 31, sub = (lane >> 4) & 1, t = lane & 15;
    int r = 2 * wv + hw;
    if (r >= nb) return;
    int s = rowptr[r], e = rowptr[r + 1];
    const u8* tab = (const u8*)items16 + (t << 4);
    float a0=0.f,a1=0.f,a2=0.f,a3=0.f,a4=0.f,a5=0.f,a6=0.f,a7=0.f;
    int base = lane & 32;
    for (int cs = s; cs < e; cs += 32) {
        int cnt = e - cs; if (cnt > 32) cnt = 32;
        int2 cv = (l31 < cnt) ? bi2[cs + l31 - S1] : make_int2(0, 0);
        int p = 0;
        for (; 2 * p + 8 <= cnt; p += 4) {
            int o0 = __shfl(cv.x, base + 2 * p + sub);
            int o1 = __shfl(cv.x, base + 2 * p + 2 + sub);
            int o2 = __shfl(cv.x, base + 2 * p + 4 + sub);
            int o3 = __shfl(cv.x, base + 2 * p + 6 + sub);
            float w0 = __int_as_float(__shfl(cv.y, base + 2 * p + sub));
            float w1 = __int_as_float(__shfl(cv.y, base + 2 * p + 2 + sub));
            float w2 = __int_as_float(__shfl(cv.y, base + 2 * p + 4 + sub));
            float w3 = __int_as_float(__shfl(cv.y, base + 2 * p + 6 + sub));
            uint4 x0 = *(const uint4*)(tab + o0);
            uint4 x1 = *(const uint4*)(tab + o1);
            uint4 x2 = *(const uint4*)(tab + o2);
            uint4 x3 = *(const uint4*)(tab + o3);
            FMA8(x0, w0) FMA8(x1, w1) FMA8(x2, w2) FMA8(x3, w3)
        }
        for (; 2 * p + 2 <= cnt; ++p) {
            int o = __shfl(cv.x, base + 2 * p + sub);
            float wt = __int_as_float(__shfl(cv.y, base + 2 * p + sub));
            uint4 x = *(const uint4*)(tab + o);
            FMA8(x, wt)
        }
        if (2 * p < cnt) {
            int o = __shfl(cv.x, base + 2 * p);
            float wt = __int_as_float(__shfl(cv.y, base + 2 * p));
            if (sub == 0) { uint4 x = *(const uint4*)(tab + o); FMA8(x, wt) }
        }
    }
    a0 += __shfl_xor(a0, 16); a1 += __shfl_xor(a1, 16);
    a2 += __shfl_xor(a2, 16); a3 += __shfl_xor(a3, 16);
    a4 += __shfl_xor(a4, 16); a5 += __shfl_xor(a5, 16);
    a6 += __shfl_xor(a6, 16); a7 += __shfl_xor(a7, 16);
    if (sub == 0) {
        float* orow = outb + (size_t)r * FD;
        ((float4*)orow)[2 * t]     = make_float4(a0, a1, a2, a3);
        ((float4*)orow)[2 * t + 1] = make_float4(a4, a5, a6, a7);
    }
}

extern "C" void kernel_launch(void* const* d_in, const int* in_sizes, int n_in,
                              void* d_out, int out_size, void* d_ws, size_t ws_size,
                              hipStream_t stream) {
    const float* users   = (const float*)d_in[0];
    const float* bundles = (const float*)d_in[1];
    const float* items   = (const float*)d_in[2];
    const float* bi_vals = (const float*)d_in[3];
    const int* ub_u = (const int*)d_in[4];
    const int* ub_b = (const int*)d_in[5];
    const int* ui_u = (const int*)d_in[6];
    const int* ui_i = (const int*)d_in[7];
    const int* bi_b = (const int*)d_in[8];
    const int* bi_i = (const int*)d_in[9];

    const int NU = in_sizes[0] / FD;
    const int NB = in_sizes[1] / FD;
    const int NI = in_sizes[2] / FD;
    const int E_BI = in_sizes[3];
    const int E_UB = in_sizes[4];
    const int E_UI = in_sizes[6];
    float* out = (float*)d_out;

    const int n1 = NU + NB, n2 = NU + NI;
    const int n12 = n1 + n2;
    const int NT = NU + NB + NI;
    const int NN = n12 + NB;                        // total CSR rows
    const int S1 = 2 * E_UB + 2 * E_UI;             // first BI slot / BI rowptr base
    const int TOT = S1 + E_BI;                      // total CSR entries
    const int ETOT = E_UB + E_UI + E_BI;

    // ---- workspace layout ----
    uint* fini16   = (uint*)d_ws;                          // NT*FDH uints
    uint* facc16   = fini16 + (size_t)NT * FDH;            // n12*FDH uints
    uint* items16  = facc16 + (size_t)n12 * FDH;           // NI*FDH uints
    u16* g8        = (u16*)(items16 + (size_t)NI * FDH);   // n12*FDH u16
    uint* fX       = (uint*)(g8 + (size_t)n12 * FDH);      // n12*32 uints (fp8) / n12*16 (fp4)
    float* fscale  = (float*)(fX + (size_t)n12 * 32);      // n12
    float* normf   = fscale + n12;                         // NT
    float* dinv    = normf + NT;                           // n12
    int* deg       = (int*)(dinv + n12);                   // NN+1
    int* rowptr    = deg + (NN + 1);                       // NN+1
    int* head      = rowptr + (NN + 1);                    // NN
    int* bsum      = head + NN;                            // 512
    int* cols      = bsum + 512;                           // S1
    int2* bi2      = (int2*)((((size_t)(cols + S1)) + 15) & ~(size_t)15);   // E_BI int2
    int2* pairLL   = (int2*)((((size_t)(bi2 + E_BI)) + 15) & ~(size_t)15);  // TOT int2

    dim3 blk(256);
    auto rows2_grid = [](int n) { return dim3((unsigned)((n + 7) / 8)); };
    auto thr_grid   = [](int n) { return dim3((unsigned)((n + 255) / 256)); };

    // ---- linked-list CSR build (one atomic pass) + fused feature prep ----
    hipMemsetAsync(head, 0xFF, (size_t)NN * 4, stream);    // head = -1
    int nblk_edges = (ETOT + 255) / 256;
    int nblk_prep  = (NT + 3) / 4;
    passA<<<dim3((unsigned)(nblk_edges + nblk_prep)), blk, 0, stream>>>(
        ub_u, ub_b, ui_u, ui_i, bi_b, bi_i, users, bundles, items,
        E_UB, E_UI, E_BI, NU, NB, n1, n2, NT, nblk_edges,
        head, pairLL, fini16, normf);
    passB<<<thr_grid(NN + 1), blk, 0, stream>>>(head, pairLL, NN, n12, deg, dinv);
    {
        int nelem = NN + 1;
        int nblk = (nelem + SCAN_ELEMS - 1) / SCAN_ELEMS;
        scan_a<<<dim3((unsigned)nblk), dim3(SCAN_TPB), 0, stream>>>(deg, rowptr, bsum, nelem);
        scan_b<<<dim3(1), dim3(512), 0, stream>>>(bsum, nblk);
        scan_c<<<dim3((unsigned)nblk), dim3(SCAN_TPB), 0, stream>>>(rowptr, bsum, nelem);
    }
    {
        int nblkC = (NN + 255) / 256;
        int nblkG = (n12 + 3) / 4;
        passC_conv<<<dim3((unsigned)(nblkC + nblkG)), blk, 0, stream>>>(
            head, pairLL, rowptr, bi_vals, NN, n12, S1, cols, bi2,
            fini16, normf, dinv, n1, NU, NB, g8, nblkC);
    }

    // ---- Layer 1 (UB + UI fused, 2 rows/wave fp8 gather; emits fp4/fp8 fX) ----
    spmm_L1<<<rows2_grid(n12), blk, 0, stream>>>(rowptr, cols, dinv, normf,
                                                 fini16, g8, facc16, fX, fscale,
                                                 n1, NU, NB, n12);
    // ---- Layer 2 (UB + UI fused, fp4 gather) + writeout ----
    spmm_L2<<<rows2_grid(n12), blk, 0, stream>>>(rowptr, cols, dinv, fini16,
                                                 facc16, fX, fscale, items16, out,
                                                 n1, NU, NB, n12);
    // ---- BI aggregation ----
    bi_gather<<<rows2_grid(NB), blk, 0, stream>>>(rowptr + n12, bi2, S1, items16,
        out + (size_t)2 * NU * FD, NB);
}